// Round 9
// baseline (92.365 us; speedup 1.0000x reference)
//
#include <hip/hip_runtime.h>
#include <math.h>

// Problem constants: B=64, IN=1024, OUT=512, T=512, V_TH=1, TAU=16
#define BATCH   64
#define INS     1024
#define OUTS    512
#define TSTEPS  512
#define TAUF    16.0f
// log2(e)/TAU for exp(t/tau) == exp2(t * LOG2E_OVER_TAU)
#define LOG2E_OVER_TAU 0.0901684400555602f

// ---------------------------------------------------------------------------
// Fused pre-kernel: blocks [0,128) tiled weight transpose w[OUT,IN]->wT[IN,OUT];
// blocks [128,192) per-batch spike prep + counting sort by activation time.
//   alpha(t-s) = e^{-t/tau} * (t*A + C) for t > s,
//   A = exp(1 + s/tau)/tau,  C = -s*A,  t_on = floor(s)+1 in [1,256].
// Record per spike (sorted by t_on): {A, int_bits(idx*OUTS/2), C, int_bits(t_on)}
// Also writes starts[b][tau], tau in [0,257]: # spikes with t_on < tau.
// Bucket scan done with wave-level __shfl_up (2 barriers, not 16).
// ---------------------------------------------------------------------------
#define TT 64
#define NTRANS ((INS / TT) * (OUTS / TT))   // 128 transpose blocks

__global__ __launch_bounds__(256) void pre_kernel(
        const float* __restrict__ w, float* __restrict__ wT,
        const float* __restrict__ in_spike, float4* __restrict__ spk,
        int* __restrict__ starts) {
    __shared__ float tile[TT][TT + 1];
    __shared__ int hist[257];
    __shared__ int cursor[257];
    __shared__ int wsum[4];

    if (blockIdx.x < NTRANS) {
        const int i0 = (blockIdx.x & (INS / TT - 1)) * TT;
        const int o0 = (blockIdx.x / (INS / TT)) * TT;
        const int c  = threadIdx.x & 63;
        const int r  = threadIdx.x >> 6;
#pragma unroll
        for (int rr = r; rr < TT; rr += 4)
            tile[rr][c] = w[(o0 + rr) * INS + i0 + c];
        __syncthreads();
#pragma unroll
        for (int rr = r; rr < TT; rr += 4)
            wT[(i0 + rr) * OUTS + o0 + c] = tile[c][rr];
        return;
    }

    const int b = blockIdx.x - NTRANS;
    const int tid = threadIdx.x;
    for (int k = tid; k < 257; k += 256) hist[k] = 0;
    __syncthreads();

    float sv[INS / 256];
    int   tv[INS / 256];
#pragma unroll
    for (int j = 0; j < INS / 256; ++j) {
        int i = tid + j * 256;
        float s = in_spike[b * INS + i];
        sv[j] = s;
        int t = (int)floorf(s) + 1;
        t = t < 1 ? 1 : (t > 256 ? 256 : t);
        tv[j] = t;
        atomicAdd(&hist[t], 1);
    }
    __syncthreads();

    // wave-shuffle inclusive scan of hist[1..256] across 4 waves
    const int lane = tid & 63;
    const int wv   = tid >> 6;
    int v = hist[tid + 1];
    int sc = v;
#pragma unroll
    for (int off = 1; off < 64; off <<= 1) {
        int n = __shfl_up(sc, off, 64);
        if (lane >= off) sc += n;
    }
    if (lane == 63) wsum[wv] = sc;
    __syncthreads();
    int base = 0;
    for (int j = 0; j < wv; ++j) base += wsum[j];
    int excl = sc + base - v;             // # spikes with t_on < tid+1
    cursor[tid + 1] = excl;
    starts[b * 258 + tid + 1] = excl;
    if (tid == 0) { starts[b * 258] = 0; starts[b * 258 + 257] = INS; }
    __syncthreads();

#pragma unroll
    for (int j = 0; j < INS / 256; ++j) {
        int i = tid + j * 256;
        int t = tv[j];
        int pos = atomicAdd(&cursor[t], 1);
        float A = expf(fmaf(sv[j], 1.0f / TAUF, 1.0f)) * (1.0f / TAUF);
        float C = -sv[j] * A;
        spk[b * INS + pos] =
            make_float4(A, __int_as_float(i * (OUTS / 2)), C, __int_as_float(t));
    }
}

// ---------------------------------------------------------------------------
// Scan kernel: time-aligned windows + LDS staging + branchless mask checks
// + 8-outstanding pass-1 (two 4-wide accumulator chains -> 8 ds_reads and
// 8 L2 gathers in flight; the R8 profile was MLP-limited at 4).
// Block = (b, 64 outputs), 1024 threads: threadIdx.x = lane (32) owning
// outputs (2x,2x+1) via float2 gathers; threadIdx.y = g (32) owning time
// window [8g+1, 8g+8] and its spikes (bucket ranges from starts[]).
//   V(t) >= 1  <=>  fma(t, SA, SC) >= exp2(t*log2e/tau).
// Windows + distributed tail partition the time axis -> atomicMin exact.
// Grid = 64*8 = 512 blocks -> exactly 2 blocks/CU = 32 waves/CU.
// ---------------------------------------------------------------------------
#define OL 32            // lanes per block (each owns 2 outputs)
#define G  32            // time windows
#define WS 8             // steps per window (G*WS = 256 covers all t_on)
#define TAIL0 257        // first spike-free time step

__global__ __launch_bounds__(OL * G, 8) void spike_scan_kernel(
        const float4* __restrict__ spk, const int* __restrict__ starts,
        const float* __restrict__ wT, float* __restrict__ out) {
    const int b = blockIdx.x;
    const int x = threadIdx.x;           // 0..31 lane
    const int g = threadIdx.y;           // 0..31 window
    const int tid = g * OL + x;

    __shared__ float4 sspk[INS];         // 16 KB
    __shared__ float2 psP0[G][OL];       // 8 KB (A0,C0)
    __shared__ float2 psP1[G][OL];       // 8 KB (A1,C1)
    __shared__ int    sSt[258];          // 1 KB
    __shared__ int    sFirst[2 * OL];    // 256 B

    sspk[tid] = spk[b * INS + tid];
    if (tid < 258) sSt[tid] = starts[b * 258 + tid];
    if (tid < 2 * OL) sFirst[tid] = TSTEPS;
    __syncthreads();

    const int w0 = g * WS + 1;           // first time step of window
    const int kBeg = sSt[w0];
    const int kEnd = sSt[w0 + WS];
    const float2* __restrict__ wT2x = (const float2*)wT + (blockIdx.y * OL + x);

    // ---- pass 1: window sums, 8-wide (two independent 4-wide chains) ----
    float pA0 = 0.f, pC0 = 0.f, pA1 = 0.f, pC1 = 0.f;
    float rA0 = 0.f, rC0 = 0.f, rA1 = 0.f, rC1 = 0.f;
    int k = kBeg;
    for (; k + 8 <= kEnd; k += 8) {
        float4 p0 = sspk[k + 0];
        float4 p1 = sspk[k + 1];
        float4 p2 = sspk[k + 2];
        float4 p3 = sspk[k + 3];
        float4 p4 = sspk[k + 4];
        float4 p5 = sspk[k + 5];
        float4 p6 = sspk[k + 6];
        float4 p7 = sspk[k + 7];
        float2 q0 = wT2x[__float_as_int(p0.y)];
        float2 q1 = wT2x[__float_as_int(p1.y)];
        float2 q2 = wT2x[__float_as_int(p2.y)];
        float2 q3 = wT2x[__float_as_int(p3.y)];
        float2 q4 = wT2x[__float_as_int(p4.y)];
        float2 q5 = wT2x[__float_as_int(p5.y)];
        float2 q6 = wT2x[__float_as_int(p6.y)];
        float2 q7 = wT2x[__float_as_int(p7.y)];
        pA0 = fmaf(q0.x, p0.x, pA0); pC0 = fmaf(q0.x, p0.z, pC0);
        pA1 = fmaf(q0.y, p0.x, pA1); pC1 = fmaf(q0.y, p0.z, pC1);
        pA0 = fmaf(q1.x, p1.x, pA0); pC0 = fmaf(q1.x, p1.z, pC0);
        pA1 = fmaf(q1.y, p1.x, pA1); pC1 = fmaf(q1.y, p1.z, pC1);
        pA0 = fmaf(q2.x, p2.x, pA0); pC0 = fmaf(q2.x, p2.z, pC0);
        pA1 = fmaf(q2.y, p2.x, pA1); pC1 = fmaf(q2.y, p2.z, pC1);
        pA0 = fmaf(q3.x, p3.x, pA0); pC0 = fmaf(q3.x, p3.z, pC0);
        pA1 = fmaf(q3.y, p3.x, pA1); pC1 = fmaf(q3.y, p3.z, pC1);
        rA0 = fmaf(q4.x, p4.x, rA0); rC0 = fmaf(q4.x, p4.z, rC0);
        rA1 = fmaf(q4.y, p4.x, rA1); rC1 = fmaf(q4.y, p4.z, rC1);
        rA0 = fmaf(q5.x, p5.x, rA0); rC0 = fmaf(q5.x, p5.z, rC0);
        rA1 = fmaf(q5.y, p5.x, rA1); rC1 = fmaf(q5.y, p5.z, rC1);
        rA0 = fmaf(q6.x, p6.x, rA0); rC0 = fmaf(q6.x, p6.z, rC0);
        rA1 = fmaf(q6.y, p6.x, rA1); rC1 = fmaf(q6.y, p6.z, rC1);
        rA0 = fmaf(q7.x, p7.x, rA0); rC0 = fmaf(q7.x, p7.z, rC0);
        rA1 = fmaf(q7.y, p7.x, rA1); rC1 = fmaf(q7.y, p7.z, rC1);
    }
    for (; k < kEnd; ++k) {
        float4 p = sspk[k];
        float2 q = wT2x[__float_as_int(p.y)];
        pA0 = fmaf(q.x, p.x, pA0); pC0 = fmaf(q.x, p.z, pC0);
        pA1 = fmaf(q.y, p.x, pA1); pC1 = fmaf(q.y, p.z, pC1);
    }
    pA0 += rA0; pC0 += rC0; pA1 += rA1; pC1 += rC1;
    psP0[g][x] = make_float2(pA0, pC0);
    psP1[g][x] = make_float2(pA1, pC1);
    __syncthreads();

    // ---- prefix over g (j<g) then totals (j>=g); no per-iter selects ----
    float SA0 = 0.f, SC0 = 0.f, SA1 = 0.f, SC1 = 0.f;
    for (int j = 0; j < g; ++j) {
        float2 a = psP0[j][x];
        float2 c = psP1[j][x];
        SA0 += a.x; SC0 += a.y; SA1 += c.x; SC1 += c.y;
    }
    float TA0 = SA0, TC0 = SC0, TA1 = SA1, TC1 = SC1;
    for (int j = g; j < G; ++j) {
        float2 a = psP0[j][x];
        float2 c = psP1[j][x];
        TA0 += a.x; TC0 += a.y; TA1 += c.x; TC1 += c.y;
    }

    // ---- pass 2: boundary-driven walk + branchless mask checks ----
    unsigned m0 = 0, m1 = 0;
    float tf = (float)w0;
    k = kBeg;
    for (int d = 0; d < WS; ++d) {
        int e = sSt[w0 + d + 1];         // spikes with t_on <= w0+d
        float dA0 = 0.f, dC0 = 0.f, dA1 = 0.f, dC1 = 0.f;
        while (k < e) {
            float4 p = sspk[k];
            float2 q = wT2x[__float_as_int(p.y)];
            dA0 = fmaf(q.x, p.x, dA0); dC0 = fmaf(q.x, p.z, dC0);
            dA1 = fmaf(q.y, p.x, dA1); dC1 = fmaf(q.y, p.z, dC1);
            ++k;
        }
        SA0 += dA0; SC0 += dC0; SA1 += dA1; SC1 += dC1;
        float ev = exp2f(tf * LOG2E_OVER_TAU);
        m0 |= (fmaf(tf, SA0, SC0) >= ev) ? (1u << d) : 0u;
        m1 |= (fmaf(tf, SA1, SC1) >= ev) ? (1u << d) : 0u;
        tf += 1.0f;
    }
    int f0 = m0 ? (w0 + __builtin_ffs(m0) - 1) : TSTEPS;
    int f1 = m1 ? (w0 + __builtin_ffs(m1) - 1) : TSTEPS;

    // ---- distributed spike-free tail [TAIL0, TSTEPS): 8 steps per g ----
    {
        const int t0 = TAIL0 + g * WS;
        unsigned n0 = 0, n1 = 0;
        float tg = (float)t0;
        for (int d = 0; d < WS; ++d) {
            if (t0 + d < TSTEPS) {
                float ev = exp2f(tg * LOG2E_OVER_TAU);
                n0 |= (fmaf(tg, TA0, TC0) >= ev) ? (1u << d) : 0u;
                n1 |= (fmaf(tg, TA1, TC1) >= ev) ? (1u << d) : 0u;
            }
            tg += 1.0f;
        }
        if (n0) f0 = min(f0, t0 + __builtin_ffs(n0) - 1);
        if (n1) f1 = min(f1, t0 + __builtin_ffs(n1) - 1);
    }

    if (f0 < TSTEPS) atomicMin(&sFirst[2 * x], f0);
    if (f1 < TSTEPS) atomicMin(&sFirst[2 * x + 1], f1);
    __syncthreads();
    if (tid < 2 * OL)
        out[b * OUTS + blockIdx.y * (2 * OL) + tid] = (float)sFirst[tid];
}

// ---------------------------------------------------------------------------
extern "C" void kernel_launch(void* const* d_in, const int* in_sizes, int n_in,
                              void* d_out, int out_size, void* d_ws, size_t ws_size,
                              hipStream_t stream) {
    const float* in_spike = (const float*)d_in[0];   // [B, IN] fp32
    const float* weight   = (const float*)d_in[1];   // [OUT, IN] fp32
    float* out = (float*)d_out;                      // [B, OUT] fp32

    // ws layout: wT 2 MB | spk 1 MB | starts 64*258 ints (~66 KB)
    float*  wT     = (float*)d_ws;
    float4* spk    = (float4*)((char*)d_ws + (size_t)INS * OUTS * sizeof(float));
    int*    starts = (int*)((char*)d_ws + (size_t)INS * OUTS * sizeof(float)
                                        + (size_t)BATCH * INS * sizeof(float4));

    pre_kernel<<<NTRANS + BATCH, 256, 0, stream>>>(weight, wT, in_spike, spk, starts);
    spike_scan_kernel<<<dim3(BATCH, OUTS / (2 * OL)), dim3(OL, G), 0, stream>>>(
        spk, starts, wT, out);
}

// Round 10
// 81.477 us; speedup vs baseline: 1.1336x; 1.1336x over previous
//
#include <hip/hip_runtime.h>
#include <math.h>

// Problem constants: B=64, IN=1024, OUT=512, T=512, V_TH=1, TAU=16
#define BATCH   64
#define INS     1024
#define OUTS    512
#define TSTEPS  512
#define TAUF    16.0f
// log2(e)/TAU for exp(t/tau) == exp2(t * LOG2E_OVER_TAU)
#define LOG2E_OVER_TAU 0.0901684400555602f

// ---------------------------------------------------------------------------
// Fused pre-kernel: blocks [0,128) tiled weight transpose w[OUT,IN]->wT[IN,OUT];
// blocks [128,192) per-batch spike prep + counting sort by activation time.
//   alpha(t-s) = e^{-t/tau} * (t*A + C) for t > s,
//   A = exp(1 + s/tau)/tau,  C = -s*A,  t_on = floor(s)+1 in [1,256].
// Record per spike (sorted by t_on): {A, int_bits(idx*OUTS/2), C, int_bits(t_on)}
// Also writes starts[b][tau], tau in [0,257]: # spikes with t_on < tau.
// ---------------------------------------------------------------------------
#define TT 64
#define NTRANS ((INS / TT) * (OUTS / TT))   // 128 transpose blocks

__global__ __launch_bounds__(256) void pre_kernel(
        const float* __restrict__ w, float* __restrict__ wT,
        const float* __restrict__ in_spike, float4* __restrict__ spk,
        int* __restrict__ starts) {
    __shared__ float tile[TT][TT + 1];
    __shared__ int hist[257];
    __shared__ int cursor[257];
    __shared__ int wsum[4];

    if (blockIdx.x < NTRANS) {
        const int i0 = (blockIdx.x & (INS / TT - 1)) * TT;
        const int o0 = (blockIdx.x / (INS / TT)) * TT;
        const int c  = threadIdx.x & 63;
        const int r  = threadIdx.x >> 6;
#pragma unroll
        for (int rr = r; rr < TT; rr += 4)
            tile[rr][c] = w[(o0 + rr) * INS + i0 + c];
        __syncthreads();
#pragma unroll
        for (int rr = r; rr < TT; rr += 4)
            wT[(i0 + rr) * OUTS + o0 + c] = tile[c][rr];
        return;
    }

    const int b = blockIdx.x - NTRANS;
    const int tid = threadIdx.x;
    for (int k = tid; k < 257; k += 256) hist[k] = 0;
    __syncthreads();

    float sv[INS / 256];
    int   tv[INS / 256];
#pragma unroll
    for (int j = 0; j < INS / 256; ++j) {
        int i = tid + j * 256;
        float s = in_spike[b * INS + i];
        sv[j] = s;
        int t = (int)floorf(s) + 1;
        t = t < 1 ? 1 : (t > 256 ? 256 : t);
        tv[j] = t;
        atomicAdd(&hist[t], 1);
    }
    __syncthreads();

    // wave-shuffle inclusive scan of hist[1..256] across 4 waves
    const int lane = tid & 63;
    const int wv   = tid >> 6;
    int v = hist[tid + 1];
    int sc = v;
#pragma unroll
    for (int off = 1; off < 64; off <<= 1) {
        int n = __shfl_up(sc, off, 64);
        if (lane >= off) sc += n;
    }
    if (lane == 63) wsum[wv] = sc;
    __syncthreads();
    int base = 0;
    for (int j = 0; j < wv; ++j) base += wsum[j];
    int excl = sc + base - v;             // # spikes with t_on < tid+1
    cursor[tid + 1] = excl;
    starts[b * 258 + tid + 1] = excl;
    if (tid == 0) { starts[b * 258] = 0; starts[b * 258 + 257] = INS; }
    __syncthreads();

#pragma unroll
    for (int j = 0; j < INS / 256; ++j) {
        int i = tid + j * 256;
        int t = tv[j];
        int pos = atomicAdd(&cursor[t], 1);
        float A = expf(fmaf(sv[j], 1.0f / TAUF, 1.0f)) * (1.0f / TAUF);
        float C = -sv[j] * A;
        spk[b * INS + pos] =
            make_float4(A, __int_as_float(i * (OUTS / 2)), C, __int_as_float(t));
    }
}

// ---------------------------------------------------------------------------
// Scan kernel, SINGLE-PASS with linear snapshots.
// Block = (b, 64 outputs), 1024 threads: threadIdx.x = lane (32) owning
// outputs (2x,2x+1) via float2 gathers; threadIdx.y = g (32) owning time
// window [8g+1, 8g+8].  The window's spikes are walked ONCE, bucket-by-
// bucket (boundaries sSt[], wave-uniform); after bucket d we snapshot the
// scalar l_d = fma(t_d, cA, cC) (linear in the running sums).  After the
// LDS prefix scan over g, the check at t_d needs no spike re-walk:
//   V(t_d) = fma(t_d, SA_prefix, SC_prefix) + l_d  >=  exp2(t_d*log2e/tau).
// Crossing bits -> mask -> ffs.  Spike-free tail [257,512) split 8 steps
// per g using totals.  Windows+tail partition the time axis -> atomicMin
// exact.  Grid = 64*8 = 512 blocks -> 2 blocks/CU = 32 waves/CU.
// ---------------------------------------------------------------------------
#define OL 32            // lanes per block (each owns 2 outputs)
#define G  32            // time windows
#define WS 8             // steps per window (G*WS = 256 covers all t_on)
#define TAIL0 257        // first spike-free time step

__global__ __launch_bounds__(OL * G, 8) void spike_scan_kernel(
        const float4* __restrict__ spk, const int* __restrict__ starts,
        const float* __restrict__ wT, float* __restrict__ out) {
    const int b = blockIdx.x;
    const int x = threadIdx.x;           // 0..31 lane
    const int g = threadIdx.y;           // 0..31 window
    const int tid = g * OL + x;

    __shared__ float4 sspk[INS];         // 16 KB
    __shared__ float2 psP0[G][OL];       // 8 KB (A0,C0)
    __shared__ float2 psP1[G][OL];       // 8 KB (A1,C1)
    __shared__ int    sSt[258];          // 1 KB
    __shared__ int    sFirst[2 * OL];    // 256 B

    sspk[tid] = spk[b * INS + tid];
    if (tid < 258) sSt[tid] = starts[b * 258 + tid];
    if (tid < 2 * OL) sFirst[tid] = TSTEPS;
    __syncthreads();

    const int w0 = g * WS + 1;           // first time step of window
    const float2* __restrict__ wT2x = (const float2*)wT + (blockIdx.y * OL + x);

    // ---- single spike walk, bucketed, with linear snapshots ----
    float cA0 = 0.f, cC0 = 0.f, cA1 = 0.f, cC1 = 0.f;
    float l00, l01, l02, l03, l04, l05, l06, l07;   // output 0 snapshots
    float l10, l11, l12, l13, l14, l15, l16, l17;   // output 1 snapshots
    int k = sSt[w0];

#define BUCKET(D, LA, LB)                                                     \
    {                                                                         \
        const int e = sSt[w0 + (D) + 1];                                      \
        for (; k + 2 <= e; k += 2) {                                          \
            float4 p0 = sspk[k + 0];                                          \
            float4 p1 = sspk[k + 1];                                          \
            float2 q0 = wT2x[__float_as_int(p0.y)];                           \
            float2 q1 = wT2x[__float_as_int(p1.y)];                           \
            cA0 = fmaf(q0.x, p0.x, cA0); cC0 = fmaf(q0.x, p0.z, cC0);         \
            cA1 = fmaf(q0.y, p0.x, cA1); cC1 = fmaf(q0.y, p0.z, cC1);         \
            cA0 = fmaf(q1.x, p1.x, cA0); cC0 = fmaf(q1.x, p1.z, cC0);         \
            cA1 = fmaf(q1.y, p1.x, cA1); cC1 = fmaf(q1.y, p1.z, cC1);         \
        }                                                                     \
        if (k < e) {                                                          \
            float4 p = sspk[k];                                               \
            float2 q = wT2x[__float_as_int(p.y)];                             \
            cA0 = fmaf(q.x, p.x, cA0); cC0 = fmaf(q.x, p.z, cC0);             \
            cA1 = fmaf(q.y, p.x, cA1); cC1 = fmaf(q.y, p.z, cC1);             \
            ++k;                                                              \
        }                                                                     \
        const float tf = (float)(w0 + (D));                                   \
        LA = fmaf(tf, cA0, cC0);                                              \
        LB = fmaf(tf, cA1, cC1);                                              \
    }

    BUCKET(0, l00, l10)
    BUCKET(1, l01, l11)
    BUCKET(2, l02, l12)
    BUCKET(3, l03, l13)
    BUCKET(4, l04, l14)
    BUCKET(5, l05, l15)
    BUCKET(6, l06, l16)
    BUCKET(7, l07, l17)
#undef BUCKET

    psP0[g][x] = make_float2(cA0, cC0);
    psP1[g][x] = make_float2(cA1, cC1);
    __syncthreads();

    // ---- prefix over g (j<g) then totals (j>=g); no per-iter selects ----
    float SA0 = 0.f, SC0 = 0.f, SA1 = 0.f, SC1 = 0.f;
    for (int j = 0; j < g; ++j) {
        float2 a = psP0[j][x];
        float2 c = psP1[j][x];
        SA0 += a.x; SC0 += a.y; SA1 += c.x; SC1 += c.y;
    }
    float TA0 = SA0, TC0 = SC0, TA1 = SA1, TC1 = SC1;
    for (int j = g; j < G; ++j) {
        float2 a = psP0[j][x];
        float2 c = psP1[j][x];
        TA0 += a.x; TC0 += a.y; TA1 += c.x; TC1 += c.y;
    }

    // ---- checks: V(t_d) = fma(t_d, SA, SC) + l_d, branchless mask ----
    unsigned m0 = 0, m1 = 0;
#define CHECK(D, LA, LB)                                                      \
    {                                                                         \
        const float tf = (float)(w0 + (D));                                   \
        const float ev = exp2f(tf * LOG2E_OVER_TAU);                          \
        m0 |= (fmaf(tf, SA0, SC0) + (LA) >= ev) ? (1u << (D)) : 0u;           \
        m1 |= (fmaf(tf, SA1, SC1) + (LB) >= ev) ? (1u << (D)) : 0u;           \
    }
    CHECK(0, l00, l10)
    CHECK(1, l01, l11)
    CHECK(2, l02, l12)
    CHECK(3, l03, l13)
    CHECK(4, l04, l14)
    CHECK(5, l05, l15)
    CHECK(6, l06, l16)
    CHECK(7, l07, l17)
#undef CHECK
    int f0 = m0 ? (w0 + __builtin_ffs(m0) - 1) : TSTEPS;
    int f1 = m1 ? (w0 + __builtin_ffs(m1) - 1) : TSTEPS;

    // ---- distributed spike-free tail [TAIL0, TSTEPS): 8 steps per g ----
    {
        const int t0 = TAIL0 + g * WS;
        unsigned n0 = 0, n1 = 0;
        float tg = (float)t0;
        for (int d = 0; d < WS; ++d) {
            if (t0 + d < TSTEPS) {
                float ev = exp2f(tg * LOG2E_OVER_TAU);
                n0 |= (fmaf(tg, TA0, TC0) >= ev) ? (1u << d) : 0u;
                n1 |= (fmaf(tg, TA1, TC1) >= ev) ? (1u << d) : 0u;
            }
            tg += 1.0f;
        }
        if (n0) f0 = min(f0, t0 + __builtin_ffs(n0) - 1);
        if (n1) f1 = min(f1, t0 + __builtin_ffs(n1) - 1);
    }

    if (f0 < TSTEPS) atomicMin(&sFirst[2 * x], f0);
    if (f1 < TSTEPS) atomicMin(&sFirst[2 * x + 1], f1);
    __syncthreads();
    if (tid < 2 * OL)
        out[b * OUTS + blockIdx.y * (2 * OL) + tid] = (float)sFirst[tid];
}

// ---------------------------------------------------------------------------
extern "C" void kernel_launch(void* const* d_in, const int* in_sizes, int n_in,
                              void* d_out, int out_size, void* d_ws, size_t ws_size,
                              hipStream_t stream) {
    const float* in_spike = (const float*)d_in[0];   // [B, IN] fp32
    const float* weight   = (const float*)d_in[1];   // [OUT, IN] fp32
    float* out = (float*)d_out;                      // [B, OUT] fp32

    // ws layout: wT 2 MB | spk 1 MB | starts 64*258 ints (~66 KB)
    float*  wT     = (float*)d_ws;
    float4* spk    = (float4*)((char*)d_ws + (size_t)INS * OUTS * sizeof(float));
    int*    starts = (int*)((char*)d_ws + (size_t)INS * OUTS * sizeof(float)
                                        + (size_t)BATCH * INS * sizeof(float4));

    pre_kernel<<<NTRANS + BATCH, 256, 0, stream>>>(weight, wT, in_spike, spk, starts);
    spike_scan_kernel<<<dim3(BATCH, OUTS / (2 * OL)), dim3(OL, G), 0, stream>>>(
        spk, starts, wT, out);
}